// Round 1
// baseline (510.948 us; speedup 1.0000x reference)
//
#include <hip/hip_runtime.h>
#include <hip/hip_bf16.h>

// Problem constants (from reference setup_inputs)
#define NB   8
#define NN   16384
#define NK   9
#define NCF  64          // feature channels
#define NCIN 66          // 2 + 64 concat channels
#define NCO  64
#define JTOT (NCIN * NK) // 594
#define KPAD 608         // 19 * 32 (MFMA K-steps)
#define ROWE 610         // LDS wf row length in bf16 elems (odd dword stride -> no bank conflicts)
#define MT   64          // points per block
#define LDS_BYTES (MT * ROWE * 2)

typedef __attribute__((ext_vector_type(8))) short frag8;  // 8 bf16 (4 VGPRs)
typedef __attribute__((ext_vector_type(4))) float frag4;  // 4 fp32 acc

__device__ __forceinline__ float leakyf(float x) { return x >= 0.f ? x : 0.1f * x; }

// Repack lin_w [64][594] fp32 (row co, col o*66+c) into bf16 Lb_t[co][j], j = c*9+o, zero-padded to 608.
__global__ void prep_lb_kernel(const float* __restrict__ lin_w, unsigned short* __restrict__ lb) {
  int idx = blockIdx.x * 256 + threadIdx.x;
  if (idx >= NCO * KPAD) return;
  int co = idx / KPAD;
  int j  = idx - co * KPAD;
  float v = 0.f;
  if (j < JTOT) {
    int c = j / NK;
    int o = j - c * NK;
    v = lin_w[co * JTOT + o * NCIN + c];
  }
  __hip_bfloat16 h = __float2bfloat16(v);
  unsigned short us;
  __builtin_memcpy(&us, &h, 2);
  lb[idx] = us;
}

__global__ __launch_bounds__(256) void pointconv_kernel(
    const float* __restrict__ xy,   // [8][2][16384][9]
    const float* __restrict__ feat, // [8][64][16384][9]
    const float* __restrict__ w1,   // [9][2]
    const float* __restrict__ b1,   // [9]
    const float* __restrict__ w2,   // [9][9]
    const float* __restrict__ b2,   // [9]
    const unsigned short* __restrict__ lb, // bf16 [64][608]
    const float* __restrict__ lin_b,       // [64]
    float* __restrict__ out) {             // [8][64][16384]
  extern __shared__ char smem[];
  __hip_bfloat16* wfs = (__hip_bfloat16*)smem;

  const int t  = threadIdx.x;
  const int p  = t & 63;          // point within tile
  const int g  = t >> 6;          // channel group / wave id
  const int b  = blockIdx.x >> 8; // 256 tiles per batch
  const int n0 = (blockIdx.x & 255) << 6;
  const int n  = n0 + p;

  // ---- Phase 1a: WeightNet -> w[9][9] (each of the 4 groups computes it redundantly) ----
  float wv[9][9];
  {
    const float* x0p = xy + (((size_t)b * 2 + 0) * NN + n) * NK;
    const float* x1p = xy + (((size_t)b * 2 + 1) * NN + n) * NK;
#pragma unroll
    for (int k = 0; k < NK; ++k) {
      float x0 = x0p[k], x1 = x1p[k];
      float h[9];
#pragma unroll
      for (int o = 0; o < 9; ++o)
        h[o] = leakyf(w1[2 * o] * x0 + w1[2 * o + 1] * x1 + b1[o]);
#pragma unroll
      for (int o = 0; o < 9; ++o) {
        float s = b2[o];
#pragma unroll
        for (int o2 = 0; o2 < 9; ++o2) s += w2[o * 9 + o2] * h[o2];
        wv[o][k] = leakyf(s);
      }
    }
  }

  // ---- Phase 1b: wf[j = c*9+o] = sum_k w[o][k] * knn[c][k], bf16 into LDS ----
  const int c0 = g * 17;
  const int c1 = (g == 3) ? NCIN : c0 + 17;
  for (int c = c0; c < c1; ++c) {
    const float* fp = (c < 2)
        ? xy   + (((size_t)b * 2   + c)       * NN + n) * NK
        : feat + (((size_t)b * NCF + (c - 2)) * NN + n) * NK;
    float f[9];
#pragma unroll
    for (int k = 0; k < NK; ++k) f[k] = fp[k];
#pragma unroll
    for (int o = 0; o < 9; ++o) {
      float s = 0.f;
#pragma unroll
      for (int k = 0; k < NK; ++k) s += wv[o][k] * f[k];
      wfs[p * ROWE + c * 9 + o] = __float2bfloat16(s);
    }
  }
  if (g == 3) {
#pragma unroll
    for (int j = JTOT; j < KPAD; ++j) wfs[p * ROWE + j] = __float2bfloat16(0.f);
  }
  __syncthreads();

  // ---- Phase 2: [64 pts x 608] @ [608 x 64 co] via mfma_f32_16x16x32_bf16 ----
  const int lane = t & 63;
  const int wvid = t >> 6;      // wave handles point rows [16*wvid, 16*wvid+16)
  const int col  = lane & 15;   // A: m index; B: n index; D: col index
  const int q    = lane >> 4;   // quad

  frag4 acc[4];
#pragma unroll
  for (int ct = 0; ct < 4; ++ct) acc[ct] = frag4{0.f, 0.f, 0.f, 0.f};

  const unsigned int* l32 = (const unsigned int*)smem;
  const int arow_u = (16 * wvid + col) * (ROWE / 2); // ROWE even -> exact

  for (int s = 0; s < KPAD / 32; ++s) {
    const int k0 = 32 * s;
    union { unsigned int u[4]; frag8 v; } ua;
    const int abase = arow_u + ((k0 + q * 8) >> 1);
    ua.u[0] = l32[abase + 0];
    ua.u[1] = l32[abase + 1];
    ua.u[2] = l32[abase + 2];
    ua.u[3] = l32[abase + 3];
#pragma unroll
    for (int ct = 0; ct < 4; ++ct) {
      const frag8* bp = (const frag8*)(lb + (ct * 16 + col) * KPAD + k0 + q * 8);
      acc[ct] = __builtin_amdgcn_mfma_f32_16x16x32_bf16(ua.v, *bp, acc[ct], 0, 0, 0);
    }
  }

  // ---- Epilogue: bias + leaky, float4 stores (D: col=lane&15 -> co, row=q*4+reg -> point) ----
  float* outbase = out + ((size_t)b * NCO) * NN;
  const int nrow = n0 + 16 * wvid + q * 4;
#pragma unroll
  for (int ct = 0; ct < 4; ++ct) {
    const int co = ct * 16 + col;
    const float bias = lin_b[co];
    float4 v;
    v.x = leakyf(acc[ct][0] + bias);
    v.y = leakyf(acc[ct][1] + bias);
    v.z = leakyf(acc[ct][2] + bias);
    v.w = leakyf(acc[ct][3] + bias);
    *(float4*)(outbase + (size_t)co * NN + nrow) = v;
  }
}

extern "C" void kernel_launch(void* const* d_in, const int* in_sizes, int n_in,
                              void* d_out, int out_size, void* d_ws, size_t ws_size,
                              hipStream_t stream) {
  const float* xy    = (const float*)d_in[0];
  const float* feat  = (const float*)d_in[1];
  const float* w1    = (const float*)d_in[2];
  const float* b1    = (const float*)d_in[3];
  const float* w2    = (const float*)d_in[4];
  const float* b2    = (const float*)d_in[5];
  const float* lw    = (const float*)d_in[6];
  const float* lbias = (const float*)d_in[7];
  float* out = (float*)d_out;
  unsigned short* lb = (unsigned short*)d_ws; // 64*608*2 = 77824 B

  hipFuncSetAttribute(reinterpret_cast<const void*>(pointconv_kernel),
                      hipFuncAttributeMaxDynamicSharedMemorySize, LDS_BYTES);

  prep_lb_kernel<<<(NCO * KPAD + 255) / 256, 256, 0, stream>>>(lw, lb);
  pointconv_kernel<<<NB * (NN / MT), 256, LDS_BYTES, stream>>>(
      xy, feat, w1, b1, w2, b2, lb, lbias, out);
}

// Round 2
// 488.811 us; speedup vs baseline: 1.0453x; 1.0453x over previous
//
#include <hip/hip_runtime.h>
#include <hip/hip_bf16.h>

// Problem constants (from reference setup_inputs)
#define NB   8
#define NN   16384
#define NK   9
#define NCF  64          // feature channels
#define NCIN 66          // 2 + 64 concat channels
#define NCO  64
#define JTOT (NCIN * NK) // 594
#define KPAD 608         // 19 * 32 (MFMA K-steps)
#define ROWE 610         // LDS wf row length in bf16 elems (odd dword stride -> conflict-free)
#define ROWU (ROWE / 2)  // 305 uints per row
#define MT   64          // points per block
#define LDS_BYTES (MT * ROWE * 2)

typedef __attribute__((ext_vector_type(8))) short frag8;  // 8 bf16 (4 VGPRs)
typedef __attribute__((ext_vector_type(4))) float frag4;  // 4 fp32 acc

__device__ __forceinline__ float leakyf(float x) { return fmaxf(x, 0.1f * x); }

__device__ __forceinline__ unsigned short f2bf(float x) {
  __hip_bfloat16 h = __float2bfloat16(x);
  unsigned short us;
  __builtin_memcpy(&us, &h, 2);
  return us;
}

// Repack lin_w [64][594] fp32 (row co, col o*66+c) into bf16 Lb_t[co][j], j = c*9+o, zero-padded to 608.
__global__ void prep_lb_kernel(const float* __restrict__ lin_w, unsigned short* __restrict__ lb) {
  int idx = blockIdx.x * 256 + threadIdx.x;
  if (idx >= NCO * KPAD) return;
  int co = idx / KPAD;
  int j  = idx - co * KPAD;
  float v = 0.f;
  if (j < JTOT) {
    int c = j / NK;
    int o = j - c * NK;
    v = lin_w[co * JTOT + o * NCIN + c];
  }
  lb[idx] = f2bf(v);
}

__global__ __launch_bounds__(256) void pointconv_kernel(
    const float* __restrict__ xy,   // [8][2][16384][9]
    const float* __restrict__ feat, // [8][64][16384][9]
    const float* __restrict__ w1,   // [9][2]
    const float* __restrict__ b1,   // [9]
    const float* __restrict__ w2,   // [9][9]
    const float* __restrict__ b2,   // [9]
    const unsigned short* __restrict__ lb, // bf16 [64][608]
    const float* __restrict__ lin_b,       // [64]
    float* __restrict__ out) {             // [8][64][16384]
  extern __shared__ char smem[];
  unsigned int* wfu = (unsigned int*)smem;  // wf rows as packed bf16 pairs

  const int t  = threadIdx.x;
  const int p  = t & 63;          // point within tile
  const int g  = t >> 6;          // channel group / wave id
  const int b  = blockIdx.x >> 8; // 256 tiles per batch
  const int n0 = (blockIdx.x & 255) << 6;
  const int n  = n0 + p;

  // ---- Phase 1a: WeightNet -> wv[9][9] (computed redundantly per group; registers) ----
  float wv[9][9];
  {
    float x0[9], x1[9];
    const float* x0p = xy + (((size_t)b * 2 + 0) * NN + n) * NK;
    const float* x1p = xy + (((size_t)b * 2 + 1) * NN + n) * NK;
#pragma unroll
    for (int k = 0; k < NK; ++k) { x0[k] = x0p[k]; x1[k] = x1p[k]; }
#pragma unroll
    for (int k = 0; k < NK; ++k) {
      float h[9];
#pragma unroll
      for (int o = 0; o < 9; ++o)
        h[o] = leakyf(w1[2 * o] * x0[k] + w1[2 * o + 1] * x1[k] + b1[o]);
#pragma unroll
      for (int o = 0; o < 9; ++o) {
        float s = b2[o];
#pragma unroll
        for (int o2 = 0; o2 < 9; ++o2) s += w2[o * 9 + o2] * h[o2];
        wv[o][k] = leakyf(s);
      }
    }
  }

  // ---- Phase 1b: wf[j = c*9+o] = sum_k wv[o][k] * knn[c][k], packed bf16 pairs to LDS ----
  // Channel split: g0:0-15, g1:16-31, g2:32-47, g3:48-65 (even chunk starts -> aligned b32 writes)
  const int cbeg = g * 16;
  float f0[4][9], f1[4][9];

  auto ldc = [&](float (&dst)[9], int c) {
    const float* fp = (c < 2)
        ? xy   + (((size_t)b * 2   + c)       * NN + n) * NK
        : feat + (((size_t)b * NCF + (c - 2)) * NN + n) * NK;
#pragma unroll
    for (int k = 0; k < NK; ++k) dst[k] = fp[k];
  };

  auto comp4 = [&](float (&f)[4][9], int c0) {
    unsigned int wo[18];
#pragma unroll
    for (int m = 0; m < 18; ++m) wo[m] = 0;
#pragma unroll
    for (int cc = 0; cc < 4; ++cc) {
#pragma unroll
      for (int o = 0; o < 9; ++o) {
        float s = wv[o][0] * f[cc][0];
#pragma unroll
        for (int k = 1; k < NK; ++k) s += wv[o][k] * f[cc][k];
        int v = cc * 9 + o;
        wo[v >> 1] |= (unsigned int)f2bf(s) << (16 * (v & 1));
      }
    }
    unsigned int* dst = wfu + p * ROWU + ((c0 * 9) >> 1);  // c0 even -> exact
#pragma unroll
    for (int m = 0; m < 18; ++m) dst[m] = wo[m];
  };

  auto comp2 = [&](float (&f)[4][9], int c0) {  // uses f[0],f[1]
    unsigned int wo[9];
#pragma unroll
    for (int m = 0; m < 9; ++m) wo[m] = 0;
#pragma unroll
    for (int cc = 0; cc < 2; ++cc) {
#pragma unroll
      for (int o = 0; o < 9; ++o) {
        float s = wv[o][0] * f[cc][0];
#pragma unroll
        for (int k = 1; k < NK; ++k) s += wv[o][k] * f[cc][k];
        int v = cc * 9 + o;
        wo[v >> 1] |= (unsigned int)f2bf(s) << (16 * (v & 1));
      }
    }
    unsigned int* dst = wfu + p * ROWU + ((c0 * 9) >> 1);
#pragma unroll
    for (int m = 0; m < 9; ++m) dst[m] = wo[m];
  };

  // Software pipeline: always one chunk of loads in flight ahead of compute.
#pragma unroll
  for (int cc = 0; cc < 4; ++cc) ldc(f0[cc], cbeg + cc);
#pragma unroll
  for (int cc = 0; cc < 4; ++cc) ldc(f1[cc], cbeg + 4 + cc);
  comp4(f0, cbeg + 0);
#pragma unroll
  for (int cc = 0; cc < 4; ++cc) ldc(f0[cc], cbeg + 8 + cc);
  comp4(f1, cbeg + 4);
#pragma unroll
  for (int cc = 0; cc < 4; ++cc) ldc(f1[cc], cbeg + 12 + cc);
  comp4(f0, cbeg + 8);
  if (g == 3) { ldc(f0[0], 64); ldc(f0[1], 65); }
  comp4(f1, cbeg + 12);
  if (g == 3) {
    comp2(f0, 64);
    // zero-pad j in [594, 608): uint indices 297..303
    unsigned int* dst = wfu + p * ROWU + 297;
#pragma unroll
    for (int m = 0; m < 7; ++m) dst[m] = 0;
  }
  __syncthreads();

  // ---- Phase 2: [64 pts x 608] @ [608 x 64 co] via mfma_f32_16x16x32_bf16 ----
  const int lane = t & 63;
  const int wvid = t >> 6;      // wave handles point rows [16*wvid, 16*wvid+16)
  const int col  = lane & 15;
  const int q    = lane >> 4;

  frag4 acc[4];
#pragma unroll
  for (int ct = 0; ct < 4; ++ct) acc[ct] = frag4{0.f, 0.f, 0.f, 0.f};

  const int arow_u = (16 * wvid + col) * ROWU;

  for (int s = 0; s < KPAD / 32; ++s) {
    const int k0 = 32 * s;
    union { unsigned int u[4]; frag8 v; } ua;
    const int abase = arow_u + ((k0 + q * 8) >> 1);
    ua.u[0] = wfu[abase + 0];
    ua.u[1] = wfu[abase + 1];
    ua.u[2] = wfu[abase + 2];
    ua.u[3] = wfu[abase + 3];
#pragma unroll
    for (int ct = 0; ct < 4; ++ct) {
      const frag8* bp = (const frag8*)(lb + (ct * 16 + col) * KPAD + k0 + q * 8);
      acc[ct] = __builtin_amdgcn_mfma_f32_16x16x32_bf16(ua.v, *bp, acc[ct], 0, 0, 0);
    }
  }

  // ---- Epilogue: bias + leaky, float4 stores (D: col -> co, row = q*4+reg -> point) ----
  float* outbase = out + ((size_t)b * NCO) * NN;
  const int nrow = n0 + 16 * wvid + q * 4;
#pragma unroll
  for (int ct = 0; ct < 4; ++ct) {
    const int co = ct * 16 + col;
    const float bias = lin_b[co];
    float4 v;
    v.x = leakyf(acc[ct][0] + bias);
    v.y = leakyf(acc[ct][1] + bias);
    v.z = leakyf(acc[ct][2] + bias);
    v.w = leakyf(acc[ct][3] + bias);
    *(float4*)(outbase + (size_t)co * NN + nrow) = v;
  }
}

extern "C" void kernel_launch(void* const* d_in, const int* in_sizes, int n_in,
                              void* d_out, int out_size, void* d_ws, size_t ws_size,
                              hipStream_t stream) {
  const float* xy    = (const float*)d_in[0];
  const float* feat  = (const float*)d_in[1];
  const float* w1    = (const float*)d_in[2];
  const float* b1    = (const float*)d_in[3];
  const float* w2    = (const float*)d_in[4];
  const float* b2    = (const float*)d_in[5];
  const float* lw    = (const float*)d_in[6];
  const float* lbias = (const float*)d_in[7];
  float* out = (float*)d_out;
  unsigned short* lb = (unsigned short*)d_ws; // 64*608*2 = 77824 B

  hipFuncSetAttribute(reinterpret_cast<const void*>(pointconv_kernel),
                      hipFuncAttributeMaxDynamicSharedMemorySize, LDS_BYTES);

  prep_lb_kernel<<<(NCO * KPAD + 255) / 256, 256, 0, stream>>>(lw, lb);
  pointconv_kernel<<<NB * (NN / MT), 256, LDS_BYTES, stream>>>(
      xy, feat, w1, b1, w2, b2, lb, lbias, out);
}